// Round 3
// baseline (1353.281 us; speedup 1.0000x reference)
//
#include <hip/hip_runtime.h>

// 2-branch PolyConv GNN + MLP head. ALL float32 (per reference), int32 indices.
// Algebra: f_k = L^k h, L(f) = f - dinv*S(f*dinv). Filter outputs are linear
// combos of f_0,f_1,f_2 -> compute Laplacian powers once per branch:
//   ortho (calc_thetas(2)): o0 = 3f0-3f1+0.75f2, o1 = 3f1-1.5f2, o2 = 0.75f2
//   sim (thetas all [4,4,4]): all three outputs = 4(f0+f1+f2)
// Storage: EVERYTHING lives in d_out (f32, N*386 elements = 77 MB):
//   - f_k stored directly in their final h_all column slots (stride 384):
//     ortho 0/64/128, sim 192/256/320; theta combos rewrite slots in place.
//   - dinv_o/dinv_s (2N f32) stashed in the logits region, overwritten by the
//     MLP at the very end.  d_ws is never touched (robust to any ws_size).

__global__ __launch_bounds__(256) void degree_kernel(const int* __restrict__ dst,
                                                     float* __restrict__ deg, int n_edges) {
    int e = blockIdx.x * 256 + threadIdx.x;
    if (e < n_edges) atomicAdd(&deg[dst[e]], 1.0f);
}

__global__ __launch_bounds__(256) void dinv_kernel(float* __restrict__ deg, int n) {
    int i = blockIdx.x * 256 + threadIdx.x;
    if (i < n) deg[i] = rsqrtf(fmaxf(deg[i], 1.0f));
}

// out[node*384 + off + j] = relu(x[node,:] @ W[:,j] + b[j]); x: n x 128 f32
__global__ __launch_bounds__(256) void in_gemm_kernel(
    const float* __restrict__ x, const float* __restrict__ W,
    const float* __restrict__ b, float* __restrict__ out, int off, int n) {
    __shared__ float Ws[128 * 64];   // 32 KB
    __shared__ float xs[4][128];
    int tid = threadIdx.x;
    const float4* wsrc = (const float4*)W;
    float4* wdst = (float4*)Ws;
    for (int i = tid; i < 2048; i += 256) wdst[i] = wsrc[i];
    int node0 = blockIdx.x * 4;
    const float4* xsrc = (const float4*)x;
    for (int i = tid; i < 128; i += 256) {     // 4 nodes x 32 float4
        int nl = i >> 5, c = i & 31;
        int node = node0 + nl;
        float4 v = make_float4(0.f, 0.f, 0.f, 0.f);
        if (node < n) v = xsrc[(long)node * 32 + c];
        xs[nl][c * 4 + 0] = v.x; xs[nl][c * 4 + 1] = v.y;
        xs[nl][c * 4 + 2] = v.z; xs[nl][c * 4 + 3] = v.w;
    }
    __syncthreads();
    int j = tid & 63, nl = tid >> 6;
    int node = node0 + nl;
    if (node >= n) return;
    float acc = b[j];
    #pragma unroll 8
    for (int k = 0; k < 128; ++k) acc = fmaf(xs[nl][k], Ws[k * 64 + j], acc);
    out[(long)node * 384 + off + j] = fmaxf(acc, 0.0f);
}

// p points at hall + off; zero the 64-wide slot for all nodes
__global__ __launch_bounds__(256) void zero_slice_kernel(float* __restrict__ p, int nf) {
    int i = blockIdx.x * 256 + threadIdx.x;
    if (i < nf) p[(long)(i >> 6) * 384 + (i & 63)] = 0.0f;
}

// fout[dst] += fin[src]*dinv[src]; wave per edge, lane per feature; stride 384
__global__ __launch_bounds__(256) void spmv_kernel(
    const int* __restrict__ src, const int* __restrict__ dst,
    const float* __restrict__ dinv, const float* __restrict__ fin,
    float* __restrict__ fout, int n_edges) {
    int e = blockIdx.x * 4 + (threadIdx.x >> 6);
    int lane = threadIdx.x & 63;
    if (e >= n_edges) return;
    int s = src[e], d = dst[e];
    float v = fin[(long)s * 384 + lane] * dinv[s];
    atomicAdd(&fout[(long)d * 384 + lane], v);
}

// fout <- fin - fout*dinv[node]   (slots of hall, stride 384)
__global__ __launch_bounds__(256) void fixup_kernel(
    const float* __restrict__ fin, float* __restrict__ fout,
    const float* __restrict__ dinv, int nf) {
    int i = blockIdx.x * 256 + threadIdx.x;
    if (i >= nf) return;
    int node = i >> 6;
    long a = (long)node * 384 + (i & 63);
    fout[a] = fin[a] - fout[a] * dinv[node];
}

// in-place theta combos, ortho slots 0/64/128
__global__ __launch_bounds__(256) void combine_ortho_kernel(float* __restrict__ h, int nf) {
    int i = blockIdx.x * 256 + threadIdx.x;
    if (i >= nf) return;
    long ob = (long)(i >> 6) * 384 + (i & 63);
    float a0 = h[ob], a1 = h[ob + 64], a2 = h[ob + 128];
    h[ob]       = 3.0f * a0 - 3.0f * a1 + 0.75f * a2;
    h[ob + 64]  = 3.0f * a1 - 1.5f * a2;
    h[ob + 128] = 0.75f * a2;
}

// in-place sim combos, slots 192/256/320: all three = 4(f0+f1+f2)
__global__ __launch_bounds__(256) void combine_sim_kernel(float* __restrict__ h, int nf) {
    int i = blockIdx.x * 256 + threadIdx.x;
    if (i >= nf) return;
    long ob = (long)(i >> 6) * 384 + (i & 63);
    float ss = 4.0f * (h[ob + 192] + h[ob + 256] + h[ob + 320]);
    h[ob + 192] = ss; h[ob + 256] = ss; h[ob + 320] = ss;
}

// logits = relu(h_all @ Wm1 + bm1) @ Wm2 + bm2
__global__ __launch_bounds__(256) void mlp_kernel(
    const float* __restrict__ hall, const float* __restrict__ Wm1,
    const float* __restrict__ bm1, const float* __restrict__ Wm2,
    const float* __restrict__ bm2, float* __restrict__ logits, int n) {
    __shared__ float Ws[128 * 64];   // 32 KB chunk of Wm1
    __shared__ float hs[4][384];     // 6 KB
    int tid = threadIdx.x;
    int wv = tid >> 6, lane = tid & 63;
    int node = blockIdx.x * 4 + wv;
    if (node < n) {
        long ob = (long)node * 384;
        for (int k = lane; k < 384; k += 64) hs[wv][k] = hall[ob + k];
    }
    float acc = bm1[lane];
    const float4* wsrc = (const float4*)Wm1;
    float4* wdst = (float4*)Ws;
    for (int c = 0; c < 3; ++c) {            // 3 chunks of 128 rows
        __syncthreads();
        for (int i = tid; i < 2048; i += 256) wdst[i] = wsrc[c * 2048 + i];
        __syncthreads();
        #pragma unroll 8
        for (int k = 0; k < 128; ++k)
            acc = fmaf(hs[wv][c * 128 + k], Ws[k * 64 + lane], acc);
    }
    float hid = fmaxf(acc, 0.0f);
    float p0 = hid * Wm2[lane * 2 + 0];
    float p1 = hid * Wm2[lane * 2 + 1];
    #pragma unroll
    for (int off = 32; off > 0; off >>= 1) {
        p0 += __shfl_down(p0, off);
        p1 += __shfl_down(p1, off);
    }
    if (node < n && lane == 0) {
        logits[(long)node * 2 + 0] = p0 + bm2[0];
        logits[(long)node * 2 + 1] = p1 + bm2[1];
    }
}

extern "C" void kernel_launch(void* const* d_in, const int* in_sizes, int n_in,
                              void* d_out, int out_size, void* d_ws, size_t ws_size,
                              hipStream_t stream) {
    const float* x     = (const float*)d_in[0];
    const float* sim_x = (const float*)d_in[1];
    const int* src     = (const int*)d_in[2];
    const int* dst     = (const int*)d_in[3];
    const int* sim_src = (const int*)d_in[4];
    const int* sim_dst = (const int*)d_in[5];
    const float* W1_o = (const float*)d_in[6];
    const float* b1_o = (const float*)d_in[7];
    const float* W1_s = (const float*)d_in[8];
    const float* b1_s = (const float*)d_in[9];
    const float* Wm1  = (const float*)d_in[10];
    const float* bm1  = (const float*)d_in[11];
    const float* Wm2  = (const float*)d_in[12];
    const float* bm2  = (const float*)d_in[13];

    const int N  = in_sizes[0] / 128;  // 50000
    const int E  = in_sizes[2];        // 800000
    const int Es = in_sizes[4];
    const int NF = N * 64;

    float* hall   = (float*)d_out;                 // N x 384
    float* lgt    = hall + (long)N * 384;          // N x 2 (final logits)
    float* dinv_o = lgt;                           // stash dinv here until MLP
    float* dinv_s = dinv_o + N;

    int nb4  = (N + 3) / 4;
    int nfb  = (NF + 255) / 256;
    int ebw  = (E + 3) / 4;
    int ebws = (Es + 3) / 4;

    // degrees -> dinv (in logits region; MLP overwrites it last)
    hipMemsetAsync(dinv_o, 0, (size_t)(2 * N) * sizeof(float), stream);
    degree_kernel<<<(E + 255) / 256, 256, 0, stream>>>(dst, dinv_o, E);
    degree_kernel<<<(Es + 255) / 256, 256, 0, stream>>>(sim_dst, dinv_s, Es);
    dinv_kernel<<<(2 * N + 255) / 256, 256, 0, stream>>>(dinv_o, 2 * N);

    // ---- ortho branch: slots 0 / 64 / 128 ----
    in_gemm_kernel<<<nb4, 256, 0, stream>>>(x, W1_o, b1_o, hall, 0, N);
    zero_slice_kernel<<<nfb, 256, 0, stream>>>(hall + 64, NF);
    spmv_kernel<<<ebw, 256, 0, stream>>>(src, dst, dinv_o, hall + 0, hall + 64, E);
    fixup_kernel<<<nfb, 256, 0, stream>>>(hall + 0, hall + 64, dinv_o, NF);
    zero_slice_kernel<<<nfb, 256, 0, stream>>>(hall + 128, NF);
    spmv_kernel<<<ebw, 256, 0, stream>>>(src, dst, dinv_o, hall + 64, hall + 128, E);
    fixup_kernel<<<nfb, 256, 0, stream>>>(hall + 64, hall + 128, dinv_o, NF);
    combine_ortho_kernel<<<nfb, 256, 0, stream>>>(hall, NF);

    // ---- sim branch: slots 192 / 256 / 320 ----
    in_gemm_kernel<<<nb4, 256, 0, stream>>>(sim_x, W1_s, b1_s, hall, 192, N);
    zero_slice_kernel<<<nfb, 256, 0, stream>>>(hall + 256, NF);
    spmv_kernel<<<ebws, 256, 0, stream>>>(sim_src, sim_dst, dinv_s, hall + 192, hall + 256, Es);
    fixup_kernel<<<nfb, 256, 0, stream>>>(hall + 192, hall + 256, dinv_s, NF);
    zero_slice_kernel<<<nfb, 256, 0, stream>>>(hall + 320, NF);
    spmv_kernel<<<ebws, 256, 0, stream>>>(sim_src, sim_dst, dinv_s, hall + 256, hall + 320, Es);
    fixup_kernel<<<nfb, 256, 0, stream>>>(hall + 256, hall + 320, dinv_s, NF);
    combine_sim_kernel<<<nfb, 256, 0, stream>>>(hall, NF);

    // ---- MLP head (overwrites dinv stash with real logits) ----
    mlp_kernel<<<nb4, 256, 0, stream>>>(hall, Wm1, bm1, Wm2, bm2, lgt, N);
}

// Round 5
// 762.554 us; speedup vs baseline: 1.7747x; 1.7747x over previous
//
#include <hip/hip_runtime.h>

// 2-branch PolyConv GNN + MLP head. float32, int32 indices.
// f_k = L^k h, L(f) = f - dinv*S(f*dinv). Filters = linear combos of f_0,f_1,f_2:
//   ortho: o0 = 3f0-3f1+0.75f2, o1 = 3f1-1.5f2, o2 = 0.75f2
//   sim:   all three = 4(f0+f1+f2)
// R5: CSR gather-SpMV (no atomics). Gather hops are PLAIN (write new slot only)
// -- fusing the theta combine into the final hop raced (R4: waves rewrote slots
// 0/64 that other waves were still reading as gather sources). Combines are
// fused only where node-local: ortho-combine inside the sim hop-1 gather
// (touches disjoint slots), sim-combine inside the MLP (own-node reads only).
// hall slots in d_out (stride 384): ortho f0/f1/f2 -> 0/64/128, sim -> 192/256/320.
// dinv (2N f32) stashed in logits region (overwritten by MLP last).
// d_ws (~7.2 MB): row_o[N+1] row_s[N+1] cnt_o[N] cnt_s[N] esrc_o[E] esrc_s[Es].

__global__ __launch_bounds__(256) void count_kernel(const int* __restrict__ dst,
                                                    int* __restrict__ cnt, int n_edges) {
    int e = blockIdx.x * 256 + threadIdx.x;
    if (e < n_edges) atomicAdd(&cnt[dst[e]], 1);
}

// one block per graph: exclusive scan cnt[0..n) -> row[0..n]
__global__ __launch_bounds__(1024) void scan_kernel(
    const int* __restrict__ cnt_o, int* __restrict__ row_o,
    const int* __restrict__ cnt_s, int* __restrict__ row_s, int n) {
    const int* cnt = (blockIdx.x == 0) ? cnt_o : cnt_s;
    int* row       = (blockIdx.x == 0) ? row_o : row_s;
    __shared__ int buf[2][1024];
    __shared__ int carry_s;
    int tid = threadIdx.x;
    if (tid == 0) carry_s = 0;
    __syncthreads();
    for (int base = 0; base < n; base += 1024) {
        int v = (base + tid < n) ? cnt[base + tid] : 0;
        buf[0][tid] = v;
        __syncthreads();
        int pp = 0;
        for (int off = 1; off < 1024; off <<= 1) {
            int val = buf[pp][tid];
            if (tid >= off) val += buf[pp][tid - off];
            buf[pp ^ 1][tid] = val;
            __syncthreads();
            pp ^= 1;
        }
        int inc = buf[pp][tid];          // inclusive scan of this chunk
        int carry = carry_s;
        if (base + tid < n) row[base + tid] = carry + inc - v;   // exclusive
        __syncthreads();
        if (tid == 1023) carry_s = carry + inc;
        __syncthreads();
    }
    if (tid == 0) row[n] = carry_s;
}

__global__ __launch_bounds__(256) void fill_kernel(
    const int* __restrict__ src, const int* __restrict__ dst,
    const int* __restrict__ row, int* __restrict__ cur,
    int* __restrict__ esrc, int n_edges) {
    int e = blockIdx.x * 256 + threadIdx.x;
    if (e >= n_edges) return;
    int d = dst[e];
    int pos = row[d] + atomicAdd(&cur[d], 1);
    esrc[pos] = src[e];
}

// dinv from CSR row diffs; dinv_o[0..N) then dinv_s[0..N) contiguous
__global__ __launch_bounds__(256) void dinv_kernel(
    const int* __restrict__ row_o, const int* __restrict__ row_s,
    float* __restrict__ dinv, int N) {
    int i = blockIdx.x * 256 + threadIdx.x;
    if (i < N) {
        int d = row_o[i + 1] - row_o[i];
        dinv[i] = rsqrtf((float)(d > 1 ? d : 1));
    } else if (i < 2 * N) {
        int j = i - N;
        int d = row_s[j + 1] - row_s[j];
        dinv[i] = rsqrtf((float)(d > 1 ? d : 1));
    }
}

// out[node*384 + off + j] = relu(x[node,:] @ W[:,j] + b[j]); x: n x 128
__global__ __launch_bounds__(256) void in_gemm_kernel(
    const float* __restrict__ x, const float* __restrict__ W,
    const float* __restrict__ b, float* __restrict__ out, int off, int n) {
    __shared__ float Ws[128 * 64];   // 32 KB
    __shared__ float xs[4][128];
    int tid = threadIdx.x;
    const float4* wsrc = (const float4*)W;
    float4* wdst = (float4*)Ws;
    for (int i = tid; i < 2048; i += 256) wdst[i] = wsrc[i];
    int node0 = blockIdx.x * 4;
    const float4* xsrc = (const float4*)x;
    for (int i = tid; i < 128; i += 256) {
        int nl = i >> 5, c = i & 31;
        int node = node0 + nl;
        float4 v = make_float4(0.f, 0.f, 0.f, 0.f);
        if (node < n) v = xsrc[(long)node * 32 + c];
        xs[nl][c * 4 + 0] = v.x; xs[nl][c * 4 + 1] = v.y;
        xs[nl][c * 4 + 2] = v.z; xs[nl][c * 4 + 3] = v.w;
    }
    __syncthreads();
    int j = tid & 63, nl = tid >> 6;
    int node = node0 + nl;
    if (node >= n) return;
    float acc = b[j];
    #pragma unroll 8
    for (int k = 0; k < 128; ++k) acc = fmaf(xs[nl][k], Ws[k * 64 + j], acc);
    out[(long)node * 384 + off + j] = fmaxf(acc, 0.0f);
}

// CSR gather SpMV + fused fixup. wave per node, lane per feature.
// Reads slot in_off (sources + own node), writes f_next to slot in_off+64 ONLY.
// combine_ortho != 0: additionally apply the ortho theta combine in place on
// slots 0/64/128 (own node only -- safe when those slots are not gather
// sources in this launch, i.e. during the sim branch).
__global__ __launch_bounds__(256) void gather_kernel(
    const int* __restrict__ row, const int* __restrict__ esrc,
    const float* __restrict__ dinv, float* __restrict__ hall,
    int in_off, int combine_ortho, int n) {
    int d = blockIdx.x * 4 + (threadIdx.x >> 6);
    if (d >= n) return;
    int lane = threadIdx.x & 63;
    int p = row[d], end = row[d + 1];
    const float* fin = hall + in_off;
    float a0 = 0.f, a1 = 0.f, a2 = 0.f, a3 = 0.f;
    for (; p + 4 <= end; p += 4) {
        int s0 = esrc[p], s1 = esrc[p + 1], s2 = esrc[p + 2], s3 = esrc[p + 3];
        a0 = fmaf(fin[(long)s0 * 384 + lane], dinv[s0], a0);
        a1 = fmaf(fin[(long)s1 * 384 + lane], dinv[s1], a1);
        a2 = fmaf(fin[(long)s2 * 384 + lane], dinv[s2], a2);
        a3 = fmaf(fin[(long)s3 * 384 + lane], dinv[s3], a3);
    }
    for (; p < end; ++p) {
        int s = esrc[p];
        a0 = fmaf(fin[(long)s * 384 + lane], dinv[s], a0);
    }
    float acc = (a0 + a1) + (a2 + a3);
    long ob = (long)d * 384 + lane;
    float fd = fin[ob];                       // f_in at dst node
    hall[ob + in_off + 64] = fd - acc * dinv[d];   // f_next
    if (combine_ortho) {
        float f0v = hall[ob], f1v = hall[ob + 64], f2v = hall[ob + 128];
        hall[ob]       = 3.0f * f0v - 3.0f * f1v + 0.75f * f2v;
        hall[ob + 64]  = 3.0f * f1v - 1.5f * f2v;
        hall[ob + 128] = 0.75f * f2v;
    }
}

// logits = relu(h_all @ Wm1 + bm1) @ Wm2 + bm2.
// Fused sim combine: slots 192/256/320 hold raw f0/f1/f2 on entry; this kernel
// computes ss = 4(f0+f1+f2), writes it to all three slots (own node only) and
// uses it in the GEMM.
__global__ __launch_bounds__(256) void mlp_kernel(
    float* __restrict__ hall, const float* __restrict__ Wm1,
    const float* __restrict__ bm1, const float* __restrict__ Wm2,
    const float* __restrict__ bm2, float* __restrict__ logits, int n) {
    __shared__ float Ws[128 * 64];   // 32 KB chunk of Wm1
    __shared__ float hs[4][384];
    int tid = threadIdx.x;
    int wv = tid >> 6, lane = tid & 63;
    int node = blockIdx.x * 4 + wv;
    if (node < n) {
        long ob = (long)node * 384;
        hs[wv][lane]       = hall[ob + lane];
        hs[wv][64 + lane]  = hall[ob + 64 + lane];
        hs[wv][128 + lane] = hall[ob + 128 + lane];
        float f0v = hall[ob + 192 + lane];
        float f1v = hall[ob + 256 + lane];
        float f2v = hall[ob + 320 + lane];
        float ss = 4.0f * (f0v + f1v + f2v);
        hs[wv][192 + lane] = ss; hs[wv][256 + lane] = ss; hs[wv][320 + lane] = ss;
        hall[ob + 192 + lane] = ss;
        hall[ob + 256 + lane] = ss;
        hall[ob + 320 + lane] = ss;
    }
    float acc = bm1[lane];
    const float4* wsrc = (const float4*)Wm1;
    float4* wdst = (float4*)Ws;
    for (int c = 0; c < 3; ++c) {
        __syncthreads();
        for (int i = tid; i < 2048; i += 256) wdst[i] = wsrc[c * 2048 + i];
        __syncthreads();
        #pragma unroll 8
        for (int k = 0; k < 128; ++k)
            acc = fmaf(hs[wv][c * 128 + k], Ws[k * 64 + lane], acc);
    }
    float hid = fmaxf(acc, 0.0f);
    float p0 = hid * Wm2[lane * 2 + 0];
    float p1 = hid * Wm2[lane * 2 + 1];
    #pragma unroll
    for (int off = 32; off > 0; off >>= 1) {
        p0 += __shfl_down(p0, off);
        p1 += __shfl_down(p1, off);
    }
    if (node < n && lane == 0) {
        logits[(long)node * 2 + 0] = p0 + bm2[0];
        logits[(long)node * 2 + 1] = p1 + bm2[1];
    }
}

extern "C" void kernel_launch(void* const* d_in, const int* in_sizes, int n_in,
                              void* d_out, int out_size, void* d_ws, size_t ws_size,
                              hipStream_t stream) {
    const float* x     = (const float*)d_in[0];
    const float* sim_x = (const float*)d_in[1];
    const int* src     = (const int*)d_in[2];
    const int* dst     = (const int*)d_in[3];
    const int* sim_src = (const int*)d_in[4];
    const int* sim_dst = (const int*)d_in[5];
    const float* W1_o = (const float*)d_in[6];
    const float* b1_o = (const float*)d_in[7];
    const float* W1_s = (const float*)d_in[8];
    const float* b1_s = (const float*)d_in[9];
    const float* Wm1  = (const float*)d_in[10];
    const float* bm1  = (const float*)d_in[11];
    const float* Wm2  = (const float*)d_in[12];
    const float* bm2  = (const float*)d_in[13];

    const int N  = in_sizes[0] / 128;  // 50000
    const int E  = in_sizes[2];        // 800000
    const int Es = in_sizes[4];

    float* hall   = (float*)d_out;                 // N x 384
    float* lgt    = hall + (long)N * 384;          // N x 2
    float* dinv_o = lgt;                           // stash until MLP
    float* dinv_s = dinv_o + N;

    int* row_o  = (int*)d_ws;          // N+1
    int* row_s  = row_o + (N + 1);     // N+1
    int* cnt_o  = row_s + (N + 1);     // N (also fill cursor)
    int* cnt_s  = cnt_o + N;           // N
    int* esrc_o = cnt_s + N;           // E
    int* esrc_s = esrc_o + E;          // Es

    int nb4 = (N + 3) / 4;
    int eb  = (E + 255) / 256;
    int ebs = (Es + 255) / 256;

    // ---- CSR build ----
    hipMemsetAsync(cnt_o, 0, (size_t)(2 * N) * sizeof(int), stream);
    count_kernel<<<eb, 256, 0, stream>>>(dst, cnt_o, E);
    count_kernel<<<ebs, 256, 0, stream>>>(sim_dst, cnt_s, Es);
    scan_kernel<<<2, 1024, 0, stream>>>(cnt_o, row_o, cnt_s, row_s, N);
    dinv_kernel<<<(2 * N + 255) / 256, 256, 0, stream>>>(row_o, row_s, dinv_o, N);
    hipMemsetAsync(cnt_o, 0, (size_t)(2 * N) * sizeof(int), stream);
    fill_kernel<<<eb, 256, 0, stream>>>(src, dst, row_o, cnt_o, esrc_o, E);
    fill_kernel<<<ebs, 256, 0, stream>>>(sim_src, sim_dst, row_s, cnt_s, esrc_s, Es);

    // ---- ortho branch: f0/f1/f2 -> slots 0 / 64 / 128 (plain hops) ----
    in_gemm_kernel<<<nb4, 256, 0, stream>>>(x, W1_o, b1_o, hall, 0, N);
    gather_kernel<<<nb4, 256, 0, stream>>>(row_o, esrc_o, dinv_o, hall, 0, 0, N);
    gather_kernel<<<nb4, 256, 0, stream>>>(row_o, esrc_o, dinv_o, hall, 64, 0, N);

    // ---- sim branch: f0/f1/f2 -> slots 192 / 256 / 320 ----
    in_gemm_kernel<<<nb4, 256, 0, stream>>>(sim_x, W1_s, b1_s, hall, 192, N);
    // hop1 also applies the ortho combine (slots 0/64/128, node-local: safe here)
    gather_kernel<<<nb4, 256, 0, stream>>>(row_s, esrc_s, dinv_s, hall, 192, 1, N);
    gather_kernel<<<nb4, 256, 0, stream>>>(row_s, esrc_s, dinv_s, hall, 256, 0, N);

    // ---- MLP head (applies sim combine; overwrites dinv stash with logits) ----
    mlp_kernel<<<nb4, 256, 0, stream>>>(hall, Wm1, bm1, Wm2, bm2, lgt, N);
}

// Round 6
// 643.021 us; speedup vs baseline: 2.1046x; 1.1859x over previous
//
#include <hip/hip_runtime.h>

// 2-branch PolyConv GNN + MLP head. float32, int32 indices.
// f_k = L^k h, L(f) = f - dinv*S(f*dinv). Filters = linear combos of f_0,f_1,f_2:
//   ortho: o0 = 3f0-3f1+0.75f2, o1 = 3f1-1.5f2, o2 = 0.75f2
//   sim:   all three = 4(f0+f1+f2)
// R6: register-tiled GEMMs (64 nodes x 64 cols / block, 4x4 micro-tile,
// ds_read_b128 fragments). CSR gather-SpMV unchanged. Sim-combine standalone
// (fusing into gather hop2 races: slots 192/256 are gather sources there).
// hall slots in d_out (stride 384): ortho f0/f1/f2 -> 0/64/128, sim -> 192/256/320.
// dinv (2N f32) stashed in logits region (overwritten by MLP last).
// d_ws (~7.2 MB): row_o[N+1] row_s[N+1] cnt_o[N] cnt_s[N] esrc_o[E] esrc_s[Es].

__global__ __launch_bounds__(256) void count_kernel(const int* __restrict__ dst,
                                                    int* __restrict__ cnt, int n_edges) {
    int e = blockIdx.x * 256 + threadIdx.x;
    if (e < n_edges) atomicAdd(&cnt[dst[e]], 1);
}

// one block per graph: exclusive scan cnt[0..n) -> row[0..n]
__global__ __launch_bounds__(1024) void scan_kernel(
    const int* __restrict__ cnt_o, int* __restrict__ row_o,
    const int* __restrict__ cnt_s, int* __restrict__ row_s, int n) {
    const int* cnt = (blockIdx.x == 0) ? cnt_o : cnt_s;
    int* row       = (blockIdx.x == 0) ? row_o : row_s;
    __shared__ int buf[2][1024];
    __shared__ int carry_s;
    int tid = threadIdx.x;
    if (tid == 0) carry_s = 0;
    __syncthreads();
    for (int base = 0; base < n; base += 1024) {
        int v = (base + tid < n) ? cnt[base + tid] : 0;
        buf[0][tid] = v;
        __syncthreads();
        int pp = 0;
        for (int off = 1; off < 1024; off <<= 1) {
            int val = buf[pp][tid];
            if (tid >= off) val += buf[pp][tid - off];
            buf[pp ^ 1][tid] = val;
            __syncthreads();
            pp ^= 1;
        }
        int inc = buf[pp][tid];
        int carry = carry_s;
        if (base + tid < n) row[base + tid] = carry + inc - v;
        __syncthreads();
        if (tid == 1023) carry_s = carry + inc;
        __syncthreads();
    }
    if (tid == 0) row[n] = carry_s;
}

__global__ __launch_bounds__(256) void fill_kernel(
    const int* __restrict__ src, const int* __restrict__ dst,
    const int* __restrict__ row, int* __restrict__ cur,
    int* __restrict__ esrc, int n_edges) {
    int e = blockIdx.x * 256 + threadIdx.x;
    if (e >= n_edges) return;
    int d = dst[e];
    int pos = row[d] + atomicAdd(&cur[d], 1);
    esrc[pos] = src[e];
}

__global__ __launch_bounds__(256) void dinv_kernel(
    const int* __restrict__ row_o, const int* __restrict__ row_s,
    float* __restrict__ dinv, int N) {
    int i = blockIdx.x * 256 + threadIdx.x;
    if (i < N) {
        int d = row_o[i + 1] - row_o[i];
        dinv[i] = rsqrtf((float)(d > 1 ? d : 1));
    } else if (i < 2 * N) {
        int j = i - N;
        int d = row_s[j + 1] - row_s[j];
        dinv[i] = rsqrtf((float)(d > 1 ? d : 1));
    }
}

// Tiled: out[node*384+off+j] = relu(x[node,:]@W[:,j] + b[j]); K=128 fixed.
// 64 nodes x 64 cols per block; thread (tx,ty) computes 4x4 tile.
__global__ __launch_bounds__(256) void in_gemm_kernel(
    const float* __restrict__ x, const float* __restrict__ W,
    const float* __restrict__ b, float* __restrict__ out, int off, int n) {
    __shared__ float xs[64][132];   // 33 KB, rows 16B-aligned (132*4=528)
    __shared__ float Wf[128][68];   // 34 KB
    int tid = threadIdx.x;
    int node0 = blockIdx.x * 64;
    const float4* wsrc = (const float4*)W;
    for (int i = tid; i < 2048; i += 256) {       // W[k][j]: k=i>>4, j4=i&15
        float4 v = wsrc[i];
        *(float4*)&Wf[i >> 4][(i & 15) * 4] = v;
    }
    const float4* xsrc = (const float4*)x;
    for (int i = tid; i < 2048; i += 256) {       // node nl=i>>5, c=i&31
        int nl = i >> 5, c = i & 31;
        int node = node0 + nl;
        float4 v = make_float4(0.f, 0.f, 0.f, 0.f);
        if (node < n) v = xsrc[(long)node * 32 + c];
        *(float4*)&xs[nl][c * 4] = v;
    }
    __syncthreads();
    int tx = tid & 15, ty = tid >> 4;
    float acc[4][4] = {};
    #pragma unroll 2
    for (int k = 0; k < 128; k += 4) {
        float4 a[4], bb[4];
        #pragma unroll
        for (int i = 0; i < 4; ++i) a[i] = *(const float4*)&xs[ty * 4 + i][k];
        #pragma unroll
        for (int j = 0; j < 4; ++j) bb[j] = *(const float4*)&Wf[k + j][tx * 4];
        #pragma unroll
        for (int i = 0; i < 4; ++i) {
            acc[i][0] = fmaf(a[i].x, bb[0].x, acc[i][0]);
            acc[i][1] = fmaf(a[i].x, bb[0].y, acc[i][1]);
            acc[i][2] = fmaf(a[i].x, bb[0].z, acc[i][2]);
            acc[i][3] = fmaf(a[i].x, bb[0].w, acc[i][3]);
            acc[i][0] = fmaf(a[i].y, bb[1].x, acc[i][0]);
            acc[i][1] = fmaf(a[i].y, bb[1].y, acc[i][1]);
            acc[i][2] = fmaf(a[i].y, bb[1].z, acc[i][2]);
            acc[i][3] = fmaf(a[i].y, bb[1].w, acc[i][3]);
            acc[i][0] = fmaf(a[i].z, bb[2].x, acc[i][0]);
            acc[i][1] = fmaf(a[i].z, bb[2].y, acc[i][1]);
            acc[i][2] = fmaf(a[i].z, bb[2].z, acc[i][2]);
            acc[i][3] = fmaf(a[i].z, bb[2].w, acc[i][3]);
            acc[i][0] = fmaf(a[i].w, bb[3].x, acc[i][0]);
            acc[i][1] = fmaf(a[i].w, bb[3].y, acc[i][1]);
            acc[i][2] = fmaf(a[i].w, bb[3].z, acc[i][2]);
            acc[i][3] = fmaf(a[i].w, bb[3].w, acc[i][3]);
        }
    }
    float4 bias = *(const float4*)&b[tx * 4];
    #pragma unroll
    for (int i = 0; i < 4; ++i) {
        int node = node0 + ty * 4 + i;
        if (node >= n) break;
        float4 r;
        r.x = fmaxf(acc[i][0] + bias.x, 0.0f);
        r.y = fmaxf(acc[i][1] + bias.y, 0.0f);
        r.z = fmaxf(acc[i][2] + bias.z, 0.0f);
        r.w = fmaxf(acc[i][3] + bias.w, 0.0f);
        *(float4*)&out[(long)node * 384 + off + tx * 4] = r;
    }
}

// CSR gather SpMV + fused fixup. wave per node, lane per feature.
// combine_ortho: also apply ortho combine (node-local; safe in sim branch).
__global__ __launch_bounds__(256) void gather_kernel(
    const int* __restrict__ row, const int* __restrict__ esrc,
    const float* __restrict__ dinv, float* __restrict__ hall,
    int in_off, int combine_ortho, int n) {
    int d = blockIdx.x * 4 + (threadIdx.x >> 6);
    if (d >= n) return;
    int lane = threadIdx.x & 63;
    int p = row[d], end = row[d + 1];
    const float* fin = hall + in_off;
    float a0 = 0.f, a1 = 0.f, a2 = 0.f, a3 = 0.f;
    for (; p + 4 <= end; p += 4) {
        int s0 = esrc[p], s1 = esrc[p + 1], s2 = esrc[p + 2], s3 = esrc[p + 3];
        a0 = fmaf(fin[(long)s0 * 384 + lane], dinv[s0], a0);
        a1 = fmaf(fin[(long)s1 * 384 + lane], dinv[s1], a1);
        a2 = fmaf(fin[(long)s2 * 384 + lane], dinv[s2], a2);
        a3 = fmaf(fin[(long)s3 * 384 + lane], dinv[s3], a3);
    }
    for (; p < end; ++p) {
        int s = esrc[p];
        a0 = fmaf(fin[(long)s * 384 + lane], dinv[s], a0);
    }
    float acc = (a0 + a1) + (a2 + a3);
    long ob = (long)d * 384 + lane;
    float fd = fin[ob];
    hall[ob + in_off + 64] = fd - acc * dinv[d];
    if (combine_ortho) {
        float f0v = hall[ob], f1v = hall[ob + 64], f2v = hall[ob + 128];
        hall[ob]       = 3.0f * f0v - 3.0f * f1v + 0.75f * f2v;
        hall[ob + 64]  = 3.0f * f1v - 1.5f * f2v;
        hall[ob + 128] = 0.75f * f2v;
    }
}

// slots 192/256/320: raw f0/f1/f2 -> all three = 4(f0+f1+f2)
__global__ __launch_bounds__(256) void combine_sim_kernel(float* __restrict__ h, int nf) {
    int i = blockIdx.x * 256 + threadIdx.x;
    if (i >= nf) return;
    long ob = (long)(i >> 6) * 384 + (i & 63);
    float ss = 4.0f * (h[ob + 192] + h[ob + 256] + h[ob + 320]);
    h[ob + 192] = ss; h[ob + 256] = ss; h[ob + 320] = ss;
}

// logits = relu(h_all @ Wm1 + bm1) @ Wm2 + bm2. Tiled like in_gemm, K=384 in
// 3 chunks; epilogue computes logits via LDS (reuses xs for hid).
__global__ __launch_bounds__(256) void mlp_kernel(
    const float* __restrict__ hall, const float* __restrict__ Wm1,
    const float* __restrict__ bm1, const float* __restrict__ Wm2,
    const float* __restrict__ bm2, float* __restrict__ logits, int n) {
    __shared__ float xs[64][132];
    __shared__ float Wf[128][68];
    int tid = threadIdx.x;
    int node0 = blockIdx.x * 64;
    int tx = tid & 15, ty = tid >> 4;
    float acc[4][4] = {};
    const float4* wsrc = (const float4*)Wm1;
    const float4* hsrc = (const float4*)hall;
    for (int c = 0; c < 3; ++c) {
        __syncthreads();
        for (int i = tid; i < 2048; i += 256)
            *(float4*)&Wf[i >> 4][(i & 15) * 4] = wsrc[c * 2048 + i];
        for (int i = tid; i < 2048; i += 256) {
            int nl = i >> 5, cc = i & 31;
            int node = node0 + nl;
            float4 v = make_float4(0.f, 0.f, 0.f, 0.f);
            if (node < n) v = hsrc[(long)node * 96 + c * 32 + cc];
            *(float4*)&xs[nl][cc * 4] = v;
        }
        __syncthreads();
        #pragma unroll 2
        for (int k = 0; k < 128; k += 4) {
            float4 a[4], bb[4];
            #pragma unroll
            for (int i = 0; i < 4; ++i) a[i] = *(const float4*)&xs[ty * 4 + i][k];
            #pragma unroll
            for (int j = 0; j < 4; ++j) bb[j] = *(const float4*)&Wf[k + j][tx * 4];
            #pragma unroll
            for (int i = 0; i < 4; ++i) {
                acc[i][0] = fmaf(a[i].x, bb[0].x, acc[i][0]);
                acc[i][1] = fmaf(a[i].x, bb[0].y, acc[i][1]);
                acc[i][2] = fmaf(a[i].x, bb[0].z, acc[i][2]);
                acc[i][3] = fmaf(a[i].x, bb[0].w, acc[i][3]);
                acc[i][0] = fmaf(a[i].y, bb[1].x, acc[i][0]);
                acc[i][1] = fmaf(a[i].y, bb[1].y, acc[i][1]);
                acc[i][2] = fmaf(a[i].y, bb[1].z, acc[i][2]);
                acc[i][3] = fmaf(a[i].y, bb[1].w, acc[i][3]);
                acc[i][0] = fmaf(a[i].z, bb[2].x, acc[i][0]);
                acc[i][1] = fmaf(a[i].z, bb[2].y, acc[i][1]);
                acc[i][2] = fmaf(a[i].z, bb[2].z, acc[i][2]);
                acc[i][3] = fmaf(a[i].z, bb[2].w, acc[i][3]);
                acc[i][0] = fmaf(a[i].w, bb[3].x, acc[i][0]);
                acc[i][1] = fmaf(a[i].w, bb[3].y, acc[i][1]);
                acc[i][2] = fmaf(a[i].w, bb[3].z, acc[i][2]);
                acc[i][3] = fmaf(a[i].w, bb[3].w, acc[i][3]);
            }
        }
    }
    // hid = relu(acc + bias) -> store into xs (reuse as hid[64][132])
    __syncthreads();
    float4 bias = *(const float4*)&bm1[tx * 4];
    #pragma unroll
    for (int i = 0; i < 4; ++i) {
        xs[ty * 4 + i][tx * 4 + 0] = fmaxf(acc[i][0] + bias.x, 0.0f);
        xs[ty * 4 + i][tx * 4 + 1] = fmaxf(acc[i][1] + bias.y, 0.0f);
        xs[ty * 4 + i][tx * 4 + 2] = fmaxf(acc[i][2] + bias.z, 0.0f);
        xs[ty * 4 + i][tx * 4 + 3] = fmaxf(acc[i][3] + bias.w, 0.0f);
    }
    __syncthreads();
    if (tid < 128) {
        int nl = tid >> 1, o = tid & 1;
        int node = node0 + nl;
        if (node < n) {
            float p = bm2[o];
            #pragma unroll 8
            for (int k = 0; k < 64; ++k) p = fmaf(xs[nl][k], Wm2[k * 2 + o], p);
            logits[(long)node * 2 + o] = p;
        }
    }
}

extern "C" void kernel_launch(void* const* d_in, const int* in_sizes, int n_in,
                              void* d_out, int out_size, void* d_ws, size_t ws_size,
                              hipStream_t stream) {
    const float* x     = (const float*)d_in[0];
    const float* sim_x = (const float*)d_in[1];
    const int* src     = (const int*)d_in[2];
    const int* dst     = (const int*)d_in[3];
    const int* sim_src = (const int*)d_in[4];
    const int* sim_dst = (const int*)d_in[5];
    const float* W1_o = (const float*)d_in[6];
    const float* b1_o = (const float*)d_in[7];
    const float* W1_s = (const float*)d_in[8];
    const float* b1_s = (const float*)d_in[9];
    const float* Wm1  = (const float*)d_in[10];
    const float* bm1  = (const float*)d_in[11];
    const float* Wm2  = (const float*)d_in[12];
    const float* bm2  = (const float*)d_in[13];

    const int N  = in_sizes[0] / 128;  // 50000
    const int E  = in_sizes[2];        // 800000
    const int Es = in_sizes[4];
    const int NF = N * 64;

    float* hall   = (float*)d_out;                 // N x 384
    float* lgt    = hall + (long)N * 384;          // N x 2
    float* dinv_o = lgt;                           // stash until MLP
    float* dinv_s = dinv_o + N;

    int* row_o  = (int*)d_ws;          // N+1
    int* row_s  = row_o + (N + 1);     // N+1
    int* cnt_o  = row_s + (N + 1);     // N (also fill cursor)
    int* cnt_s  = cnt_o + N;           // N
    int* esrc_o = cnt_s + N;           // E
    int* esrc_s = esrc_o + E;          // Es

    int nb4  = (N + 3) / 4;
    int nb64 = (N + 63) / 64;
    int nfb  = (NF + 255) / 256;
    int eb   = (E + 255) / 256;
    int ebs  = (Es + 255) / 256;

    // ---- CSR build ----
    hipMemsetAsync(cnt_o, 0, (size_t)(2 * N) * sizeof(int), stream);
    count_kernel<<<eb, 256, 0, stream>>>(dst, cnt_o, E);
    count_kernel<<<ebs, 256, 0, stream>>>(sim_dst, cnt_s, Es);
    scan_kernel<<<2, 1024, 0, stream>>>(cnt_o, row_o, cnt_s, row_s, N);
    dinv_kernel<<<(2 * N + 255) / 256, 256, 0, stream>>>(row_o, row_s, dinv_o, N);
    hipMemsetAsync(cnt_o, 0, (size_t)(2 * N) * sizeof(int), stream);
    fill_kernel<<<eb, 256, 0, stream>>>(src, dst, row_o, cnt_o, esrc_o, E);
    fill_kernel<<<ebs, 256, 0, stream>>>(sim_src, sim_dst, row_s, cnt_s, esrc_s, Es);

    // ---- ortho branch: f0/f1/f2 -> slots 0 / 64 / 128 ----
    in_gemm_kernel<<<nb64, 256, 0, stream>>>(x, W1_o, b1_o, hall, 0, N);
    gather_kernel<<<nb4, 256, 0, stream>>>(row_o, esrc_o, dinv_o, hall, 0, 0, N);
    gather_kernel<<<nb4, 256, 0, stream>>>(row_o, esrc_o, dinv_o, hall, 64, 0, N);

    // ---- sim branch: f0/f1/f2 -> slots 192 / 256 / 320 ----
    in_gemm_kernel<<<nb64, 256, 0, stream>>>(sim_x, W1_s, b1_s, hall, 192, N);
    gather_kernel<<<nb4, 256, 0, stream>>>(row_s, esrc_s, dinv_s, hall, 192, 1, N);
    gather_kernel<<<nb4, 256, 0, stream>>>(row_s, esrc_s, dinv_s, hall, 256, 0, N);

    // ---- sim combine (standalone; racy anywhere else) ----
    combine_sim_kernel<<<nfb, 256, 0, stream>>>(hall, NF);

    // ---- MLP head (overwrites dinv stash with logits) ----
    mlp_kernel<<<nb64, 256, 0, stream>>>(hall, Wm1, bm1, Wm2, bm2, lgt, N);
}

// Round 7
// 570.821 us; speedup vs baseline: 2.3708x; 1.1265x over previous
//
#include <hip/hip_runtime.h>

// 2-branch PolyConv GNN + MLP head. float32, int32 indices.
// f_k = L^k h, L(f) = f - dinv*S(f*dinv). Filters = linear combos of f_0,f_1,f_2:
//   ortho: o0 = 3f0-3f1+0.75f2, o1 = 3f1-1.5f2, o2 = 0.75f2
//   sim:   all three = 4(f0+f1+f2)
// R7: (1) 3-phase multi-block scan (R6's 2-block scan was 68 us @ 0.3% occ),
// dinv fused into scan phase 3. (2) Same-hop gathers of both graphs merged in
// one launch (disjoint slots -> race-free; more in-flight loads when
// latency-bound). (3) One combined theta-combine kernel (both branches).
// hall slots in d_out (stride 384): ortho f0/f1/f2 -> 0/64/128, sim -> 192/256/320.
// dinv (2N f32) lives in logits region (overwritten by MLP last).
// d_ws: row_o[N+1] row_s[N+1] cnt[2N] esrc_o[E] esrc_s[Es] part[2B].

__global__ __launch_bounds__(256) void count_kernel(const int* __restrict__ dst,
                                                    int* __restrict__ cnt, int n_edges) {
    int e = blockIdx.x * 256 + threadIdx.x;
    if (e < n_edges) atomicAdd(&cnt[dst[e]], 1);
}

// Phase 1: per-1024-chunk sums. grid = 2*B, cnt = [graph0 N | graph1 N].
__global__ __launch_bounds__(256) void scan_p1(const int* __restrict__ cnt,
                                               int* __restrict__ part, int N, int B) {
    int g = blockIdx.x / B, c = blockIdx.x - g * B;
    const int* p = cnt + (long)g * N;
    int tid = threadIdx.x, base = c << 10;
    int s = 0;
    #pragma unroll
    for (int q = 0; q < 4; ++q) {
        int i = base + q * 256 + tid;
        if (i < N) s += p[i];
    }
    #pragma unroll
    for (int off = 32; off > 0; off >>= 1) s += __shfl_down(s, off);
    __shared__ int ws[4];
    if ((tid & 63) == 0) ws[tid >> 6] = s;
    __syncthreads();
    if (tid == 0) part[blockIdx.x] = ws[0] + ws[1] + ws[2] + ws[3];
}

// Phase 2: exclusive scan of B partials per graph (B <= 64). grid = 2 x 64.
__global__ __launch_bounds__(64) void scan_p2(int* __restrict__ part,
                                              int* __restrict__ row_o,
                                              int* __restrict__ row_s, int N, int B) {
    int g = blockIdx.x, t = threadIdx.x;
    int v = (t < B) ? part[g * B + t] : 0;
    int inc = v;
    #pragma unroll
    for (int off = 1; off < 64; off <<= 1) {
        int u = __shfl_up(inc, off);
        if (t >= off) inc += u;
    }
    if (t < B) part[g * B + t] = inc - v;          // exclusive chunk offsets
    int total = __shfl(inc, 63);
    if (t == 0) (g == 0 ? row_o : row_s)[N] = total;
}

// Phase 3: block-local exclusive scan + chunk offset -> row; dinv fused.
__global__ __launch_bounds__(256) void scan_p3(const int* __restrict__ cnt,
                                               const int* __restrict__ part,
                                               int* __restrict__ row_o, int* __restrict__ row_s,
                                               float* __restrict__ dinv, int N, int B) {
    int g = blockIdx.x / B, c = blockIdx.x - g * B;
    int tid = threadIdx.x;
    int base = (c << 10) + tid * 4;
    const int* p = cnt + (long)g * N;
    int* row = (g == 0) ? row_o : row_s;
    float* dv = dinv + (long)g * N;
    int v[4];
    #pragma unroll
    for (int q = 0; q < 4; ++q) { int i = base + q; v[q] = (i < N) ? p[i] : 0; }
    int s = v[0] + v[1] + v[2] + v[3];
    int inc = s;
    #pragma unroll
    for (int off = 1; off < 64; off <<= 1) {
        int u = __shfl_up(inc, off);
        if ((tid & 63) >= off) inc += u;
    }
    __shared__ int wt[4];
    if ((tid & 63) == 63) wt[tid >> 6] = inc;
    __syncthreads();
    int wo = 0;
    for (int w = 0; w < (tid >> 6); ++w) wo += wt[w];
    int ex = part[blockIdx.x] + wo + inc - s;
    #pragma unroll
    for (int q = 0; q < 4; ++q) {
        int i = base + q;
        if (i < N) {
            row[i] = ex;
            dv[i] = rsqrtf((float)(v[q] > 1 ? v[q] : 1));
            ex += v[q];
        }
    }
}

__global__ __launch_bounds__(256) void fill_kernel(
    const int* __restrict__ src, const int* __restrict__ dst,
    const int* __restrict__ row, int* __restrict__ cur,
    int* __restrict__ esrc, int n_edges) {
    int e = blockIdx.x * 256 + threadIdx.x;
    if (e >= n_edges) return;
    int d = dst[e];
    int pos = row[d] + atomicAdd(&cur[d], 1);
    esrc[pos] = src[e];
}

// Tiled: out[node*384+off+j] = relu(x[node,:]@W[:,j] + b[j]); K=128.
__global__ __launch_bounds__(256) void in_gemm_kernel(
    const float* __restrict__ x, const float* __restrict__ W,
    const float* __restrict__ b, float* __restrict__ out, int off, int n) {
    __shared__ float xs[64][132];
    __shared__ float Wf[128][68];
    int tid = threadIdx.x;
    int node0 = blockIdx.x * 64;
    const float4* wsrc = (const float4*)W;
    for (int i = tid; i < 2048; i += 256)
        *(float4*)&Wf[i >> 4][(i & 15) * 4] = wsrc[i];
    const float4* xsrc = (const float4*)x;
    for (int i = tid; i < 2048; i += 256) {
        int nl = i >> 5, c = i & 31;
        int node = node0 + nl;
        float4 v = make_float4(0.f, 0.f, 0.f, 0.f);
        if (node < n) v = xsrc[(long)node * 32 + c];
        *(float4*)&xs[nl][c * 4] = v;
    }
    __syncthreads();
    int tx = tid & 15, ty = tid >> 4;
    float acc[4][4] = {};
    #pragma unroll 2
    for (int k = 0; k < 128; k += 4) {
        float4 a[4], bb[4];
        #pragma unroll
        for (int i = 0; i < 4; ++i) a[i] = *(const float4*)&xs[ty * 4 + i][k];
        #pragma unroll
        for (int j = 0; j < 4; ++j) bb[j] = *(const float4*)&Wf[k + j][tx * 4];
        #pragma unroll
        for (int i = 0; i < 4; ++i) {
            acc[i][0] = fmaf(a[i].x, bb[0].x, acc[i][0]);
            acc[i][1] = fmaf(a[i].x, bb[0].y, acc[i][1]);
            acc[i][2] = fmaf(a[i].x, bb[0].z, acc[i][2]);
            acc[i][3] = fmaf(a[i].x, bb[0].w, acc[i][3]);
            acc[i][0] = fmaf(a[i].y, bb[1].x, acc[i][0]);
            acc[i][1] = fmaf(a[i].y, bb[1].y, acc[i][1]);
            acc[i][2] = fmaf(a[i].y, bb[1].z, acc[i][2]);
            acc[i][3] = fmaf(a[i].y, bb[1].w, acc[i][3]);
            acc[i][0] = fmaf(a[i].z, bb[2].x, acc[i][0]);
            acc[i][1] = fmaf(a[i].z, bb[2].y, acc[i][1]);
            acc[i][2] = fmaf(a[i].z, bb[2].z, acc[i][2]);
            acc[i][3] = fmaf(a[i].z, bb[2].w, acc[i][3]);
            acc[i][0] = fmaf(a[i].w, bb[3].x, acc[i][0]);
            acc[i][1] = fmaf(a[i].w, bb[3].y, acc[i][1]);
            acc[i][2] = fmaf(a[i].w, bb[3].z, acc[i][2]);
            acc[i][3] = fmaf(a[i].w, bb[3].w, acc[i][3]);
        }
    }
    float4 bias = *(const float4*)&b[tx * 4];
    #pragma unroll
    for (int i = 0; i < 4; ++i) {
        int node = node0 + ty * 4 + i;
        if (node >= n) break;
        float4 r;
        r.x = fmaxf(acc[i][0] + bias.x, 0.0f);
        r.y = fmaxf(acc[i][1] + bias.y, 0.0f);
        r.z = fmaxf(acc[i][2] + bias.z, 0.0f);
        r.w = fmaxf(acc[i][3] + bias.w, 0.0f);
        *(float4*)&out[(long)node * 384 + off + tx * 4] = r;
    }
}

// Merged CSR gather SpMV + fused fixup for BOTH graphs in one launch.
// blocks [0,nb): graph o (read in_off_o, write in_off_o+64)
// blocks [nb,2nb): graph s (read in_off_s, write in_off_s+64)  -- disjoint slots.
__global__ __launch_bounds__(256) void gather2_kernel(
    const int* __restrict__ row_o, const int* __restrict__ esrc_o, const float* __restrict__ dinv_o,
    const int* __restrict__ row_s, const int* __restrict__ esrc_s, const float* __restrict__ dinv_s,
    float* __restrict__ hall, int in_off_o, int in_off_s, int n, int nb) {
    int b = blockIdx.x;
    const int* row; const int* esrc; const float* dinv; int in_off;
    if (b < nb) { row = row_o; esrc = esrc_o; dinv = dinv_o; in_off = in_off_o; }
    else { b -= nb; row = row_s; esrc = esrc_s; dinv = dinv_s; in_off = in_off_s; }
    int d = b * 4 + (threadIdx.x >> 6);
    if (d >= n) return;
    int lane = threadIdx.x & 63;
    int p = row[d], end = row[d + 1];
    const float* fin = hall + in_off;
    float a0 = 0.f, a1 = 0.f, a2 = 0.f, a3 = 0.f;
    for (; p + 4 <= end; p += 4) {
        int s0 = esrc[p], s1 = esrc[p + 1], s2 = esrc[p + 2], s3 = esrc[p + 3];
        a0 = fmaf(fin[(long)s0 * 384 + lane], dinv[s0], a0);
        a1 = fmaf(fin[(long)s1 * 384 + lane], dinv[s1], a1);
        a2 = fmaf(fin[(long)s2 * 384 + lane], dinv[s2], a2);
        a3 = fmaf(fin[(long)s3 * 384 + lane], dinv[s3], a3);
    }
    for (; p < end; ++p) {
        int s = esrc[p];
        a0 = fmaf(fin[(long)s * 384 + lane], dinv[s], a0);
    }
    float acc = (a0 + a1) + (a2 + a3);
    long ob = (long)d * 384 + lane;
    hall[ob + in_off + 64] = fin[ob] - acc * dinv[d];
}

// Both theta combines, one streaming pass (node-local, race-free standalone).
__global__ __launch_bounds__(256) void combine_kernel(float* __restrict__ h, int nf) {
    int i = blockIdx.x * 256 + threadIdx.x;
    if (i >= nf) return;
    long ob = (long)(i >> 6) * 384 + (i & 63);
    float f0v = h[ob], f1v = h[ob + 64], f2v = h[ob + 128];
    h[ob]       = 3.0f * f0v - 3.0f * f1v + 0.75f * f2v;
    h[ob + 64]  = 3.0f * f1v - 1.5f * f2v;
    h[ob + 128] = 0.75f * f2v;
    float ss = 4.0f * (h[ob + 192] + h[ob + 256] + h[ob + 320]);
    h[ob + 192] = ss; h[ob + 256] = ss; h[ob + 320] = ss;
}

// logits = relu(h_all @ Wm1 + bm1) @ Wm2 + bm2. Tiled, K=384 in 3 chunks.
__global__ __launch_bounds__(256) void mlp_kernel(
    const float* __restrict__ hall, const float* __restrict__ Wm1,
    const float* __restrict__ bm1, const float* __restrict__ Wm2,
    const float* __restrict__ bm2, float* __restrict__ logits, int n) {
    __shared__ float xs[64][132];
    __shared__ float Wf[128][68];
    int tid = threadIdx.x;
    int node0 = blockIdx.x * 64;
    int tx = tid & 15, ty = tid >> 4;
    float acc[4][4] = {};
    const float4* wsrc = (const float4*)Wm1;
    const float4* hsrc = (const float4*)hall;
    for (int c = 0; c < 3; ++c) {
        __syncthreads();
        for (int i = tid; i < 2048; i += 256)
            *(float4*)&Wf[i >> 4][(i & 15) * 4] = wsrc[c * 2048 + i];
        for (int i = tid; i < 2048; i += 256) {
            int nl = i >> 5, cc = i & 31;
            int node = node0 + nl;
            float4 v = make_float4(0.f, 0.f, 0.f, 0.f);
            if (node < n) v = hsrc[(long)node * 96 + c * 32 + cc];
            *(float4*)&xs[nl][cc * 4] = v;
        }
        __syncthreads();
        #pragma unroll 2
        for (int k = 0; k < 128; k += 4) {
            float4 a[4], bb[4];
            #pragma unroll
            for (int i = 0; i < 4; ++i) a[i] = *(const float4*)&xs[ty * 4 + i][k];
            #pragma unroll
            for (int j = 0; j < 4; ++j) bb[j] = *(const float4*)&Wf[k + j][tx * 4];
            #pragma unroll
            for (int i = 0; i < 4; ++i) {
                acc[i][0] = fmaf(a[i].x, bb[0].x, acc[i][0]);
                acc[i][1] = fmaf(a[i].x, bb[0].y, acc[i][1]);
                acc[i][2] = fmaf(a[i].x, bb[0].z, acc[i][2]);
                acc[i][3] = fmaf(a[i].x, bb[0].w, acc[i][3]);
                acc[i][0] = fmaf(a[i].y, bb[1].x, acc[i][0]);
                acc[i][1] = fmaf(a[i].y, bb[1].y, acc[i][1]);
                acc[i][2] = fmaf(a[i].y, bb[1].z, acc[i][2]);
                acc[i][3] = fmaf(a[i].y, bb[1].w, acc[i][3]);
                acc[i][0] = fmaf(a[i].z, bb[2].x, acc[i][0]);
                acc[i][1] = fmaf(a[i].z, bb[2].y, acc[i][1]);
                acc[i][2] = fmaf(a[i].z, bb[2].z, acc[i][2]);
                acc[i][3] = fmaf(a[i].z, bb[2].w, acc[i][3]);
                acc[i][0] = fmaf(a[i].w, bb[3].x, acc[i][0]);
                acc[i][1] = fmaf(a[i].w, bb[3].y, acc[i][1]);
                acc[i][2] = fmaf(a[i].w, bb[3].z, acc[i][2]);
                acc[i][3] = fmaf(a[i].w, bb[3].w, acc[i][3]);
            }
        }
    }
    __syncthreads();
    float4 bias = *(const float4*)&bm1[tx * 4];
    #pragma unroll
    for (int i = 0; i < 4; ++i) {
        xs[ty * 4 + i][tx * 4 + 0] = fmaxf(acc[i][0] + bias.x, 0.0f);
        xs[ty * 4 + i][tx * 4 + 1] = fmaxf(acc[i][1] + bias.y, 0.0f);
        xs[ty * 4 + i][tx * 4 + 2] = fmaxf(acc[i][2] + bias.z, 0.0f);
        xs[ty * 4 + i][tx * 4 + 3] = fmaxf(acc[i][3] + bias.w, 0.0f);
    }
    __syncthreads();
    if (tid < 128) {
        int nl = tid >> 1, o = tid & 1;
        int node = node0 + nl;
        if (node < n) {
            float p = bm2[o];
            #pragma unroll 8
            for (int k = 0; k < 64; ++k) p = fmaf(xs[nl][k], Wm2[k * 2 + o], p);
            logits[(long)node * 2 + o] = p;
        }
    }
}

extern "C" void kernel_launch(void* const* d_in, const int* in_sizes, int n_in,
                              void* d_out, int out_size, void* d_ws, size_t ws_size,
                              hipStream_t stream) {
    const float* x     = (const float*)d_in[0];
    const float* sim_x = (const float*)d_in[1];
    const int* src     = (const int*)d_in[2];
    const int* dst     = (const int*)d_in[3];
    const int* sim_src = (const int*)d_in[4];
    const int* sim_dst = (const int*)d_in[5];
    const float* W1_o = (const float*)d_in[6];
    const float* b1_o = (const float*)d_in[7];
    const float* W1_s = (const float*)d_in[8];
    const float* b1_s = (const float*)d_in[9];
    const float* Wm1  = (const float*)d_in[10];
    const float* bm1  = (const float*)d_in[11];
    const float* Wm2  = (const float*)d_in[12];
    const float* bm2  = (const float*)d_in[13];

    const int N  = in_sizes[0] / 128;  // 50000
    const int E  = in_sizes[2];        // 800000
    const int Es = in_sizes[4];
    const int NF = N * 64;
    const int B  = (N + 1023) >> 10;   // chunks per graph (49; must be <= 64)

    float* hall = (float*)d_out;                 // N x 384
    float* lgt  = hall + (long)N * 384;          // N x 2
    float* dinv = lgt;                           // [dinv_o N | dinv_s N] until MLP
    float* dinv_o = dinv;
    float* dinv_s = dinv + N;

    int* row_o  = (int*)d_ws;          // N+1
    int* row_s  = row_o + (N + 1);     // N+1
    int* cnt    = row_s + (N + 1);     // 2N (counts, then fill cursors)
    int* esrc_o = cnt + 2 * N;         // E
    int* esrc_s = esrc_o + E;          // Es
    int* part   = esrc_s + Es;         // 2B

    int nb4  = (N + 3) / 4;
    int nb64 = (N + 63) / 64;
    int nfb  = (NF + 255) / 256;
    int eb   = (E + 255) / 256;
    int ebs  = (Es + 255) / 256;

    // ---- CSR build ----
    hipMemsetAsync(cnt, 0, (size_t)(2 * N) * sizeof(int), stream);
    count_kernel<<<eb, 256, 0, stream>>>(dst, cnt, E);
    count_kernel<<<ebs, 256, 0, stream>>>(sim_dst, cnt + N, Es);
    scan_p1<<<2 * B, 256, 0, stream>>>(cnt, part, N, B);
    scan_p2<<<2, 64, 0, stream>>>(part, row_o, row_s, N, B);
    scan_p3<<<2 * B, 256, 0, stream>>>(cnt, part, row_o, row_s, dinv, N, B);
    hipMemsetAsync(cnt, 0, (size_t)(2 * N) * sizeof(int), stream);
    fill_kernel<<<eb, 256, 0, stream>>>(src, dst, row_o, cnt, esrc_o, E);
    fill_kernel<<<ebs, 256, 0, stream>>>(sim_src, sim_dst, row_s, cnt + N, esrc_s, Es);

    // ---- input GEMMs: ortho -> slot 0, sim -> slot 192 ----
    in_gemm_kernel<<<nb64, 256, 0, stream>>>(x, W1_o, b1_o, hall, 0, N);
    in_gemm_kernel<<<nb64, 256, 0, stream>>>(sim_x, W1_s, b1_s, hall, 192, N);

    // ---- merged hops: hop1 (0->64, 192->256), hop2 (64->128, 256->320) ----
    gather2_kernel<<<2 * nb4, 256, 0, stream>>>(row_o, esrc_o, dinv_o,
                                                row_s, esrc_s, dinv_s,
                                                hall, 0, 192, N, nb4);
    gather2_kernel<<<2 * nb4, 256, 0, stream>>>(row_o, esrc_o, dinv_o,
                                                row_s, esrc_s, dinv_s,
                                                hall, 64, 256, N, nb4);

    // ---- theta combines (both branches, node-local) ----
    combine_kernel<<<nfb, 256, 0, stream>>>(hall, NF);

    // ---- MLP head (overwrites dinv stash with logits) ----
    mlp_kernel<<<nb64, 256, 0, stream>>>(hall, Wm1, bm1, Wm2, bm2, lgt, N);
}